// Round 3
// baseline (203.453 us; speedup 1.0000x reference)
//
#include <hip/hip_runtime.h>

#define H 256
#define W 256
#define W4 (W / 4)            // 64 float4 per image row
#define OWID 250
#define NIMG 256              // B*D
#define BAND 10               // output rows per wave; 25*10 = 250 exactly
#define NBANDS 25
#define NBLK (NBANDS * NIMG)  // 6400 partials
#define RIN 16                // input rows per band: BAND + 6, uniform for ALL bands
#define WPB 4                 // waves per block
#define NBLOCKS (NBLK / WPB)  // 1600 blocks of 256 threads

__device__ __forceinline__ float4 f4zero() { return make_float4(0.f, 0.f, 0.f, 0.f); }

__global__ __launch_bounds__(256, 8) void ssim_band_kernel(
    const float* __restrict__ X, const float* __restrict__ Y,
    float* __restrict__ partial)
{
    // 4 independent waves per block (no barriers, no LDS). Single-wave blocks
    // hit the ~16-workgroup/CU residency cap at ~10 waves/CU (33% occupancy,
    // round-2 counters); 4-wave blocks at VGPR<=64 allow 8 blocks/CU = 32
    // waves/CU. Wave body is identical to round 2 (60 VGPR, verified).
    const int lane = threadIdx.x & 63;          // 0..63, owns cols 4*lane..+3
    const int wid  = blockIdx.x * WPB + (threadIdx.x >> 6);  // 0..6399
    const int img  = wid / NBANDS;              // 0..255
    const int band = wid % NBANDS;              // 0..24 (adjacent bands share
                                                //        halo rows -> L1/L2)
    const int r0 = band * BAND;

    const float4* Xp = (const float4*)X + ((size_t)img * H + r0) * W4 + lane;
    const float4* Yp = (const float4*)Y + ((size_t)img * H + r0) * W4 + lane;

    // 7-deep circular history of raw x,y (registers; all indices static).
    float4 xh[7], yh[7];
    // 4 vertical moments: sx, sy, sxy, and spp = Σ(x²+y²).
    float4 sx = f4zero(), sy = f4zero(), sxy = f4zero(), spp = f4zero();

    // Depth-2 prefetch pipeline.
    float4 px[2], py[2];
    px[0] = Xp[0];      py[0] = Yp[0];
    px[1] = Xp[W4];     py[1] = Yp[W4];
    xh[6] = f4zero();   yh[6] = f4zero();   // row-6 subtracts nothing

    // SSIM constants with 1/49 (=a) and 49/48 (=covn) folded in.
    const float C1  = 1e-4f;            // (0.01)^2
    const float C2  = 9e-4f;            // (0.03)^2
    const float AA  = 1.f / 2401.f;     // a^2
    const float C2A = 2.f / 2401.f;     // 2 a^2
    const float T1  = 1.f / 24.f;       // 2 covn a
    const float T2  = -1.f / 1176.f;    // -2 covn a^2
    const float T3  = 1.f / 48.f;       // covn a
    const float T4  = -1.f / 2352.f;    // -covn a^2
    float lsum = 0.0f;

    #pragma unroll
    for (int r = 0; r < RIN; ++r) {
        // Consume row r (loaded 2 iterations ago), then refill the slot with
        // row r+2 so 2 row-pairs stay in flight.
        const float4 xn = px[r & 1], yn = py[r & 1];
        if (r + 2 < RIN) {
            px[r & 1] = Xp[(r + 2) * W4];
            py[r & 1] = Yp[(r + 2) * W4];
        }

        if (r < 6) {
            // Prologue rows: accumulate only.
            xh[r] = xn; yh[r] = yn;
            sx.x += xn.x; sx.y += xn.y; sx.z += xn.z; sx.w += xn.w;
            sy.x += yn.x; sy.y += yn.y; sy.z += yn.z; sy.w += yn.w;
            sxy.x = fmaf(xn.x, yn.x, sxy.x);
            sxy.y = fmaf(xn.y, yn.y, sxy.y);
            sxy.z = fmaf(xn.z, yn.z, sxy.z);
            sxy.w = fmaf(xn.w, yn.w, sxy.w);
            spp.x = fmaf(xn.x, xn.x, fmaf(yn.x, yn.x, spp.x));
            spp.y = fmaf(xn.y, xn.y, fmaf(yn.y, yn.y, spp.y));
            spp.z = fmaf(xn.z, xn.z, fmaf(yn.z, yn.z, spp.z));
            spp.w = fmaf(xn.w, xn.w, fmaf(yn.w, yn.w, spp.w));
        } else {
            const int slot = r % 7;            // static under full unroll
            const float4 xo = xh[slot], yo = yh[slot];

            // Vertical slide: + entering row r, - leaving row r-7.
            sx.x += xn.x - xo.x; sx.y += xn.y - xo.y;
            sx.z += xn.z - xo.z; sx.w += xn.w - xo.w;
            sy.x += yn.x - yo.x; sy.y += yn.y - yo.y;
            sy.z += yn.z - yo.z; sy.w += yn.w - yo.w;
            sxy.x = fmaf(xn.x, yn.x, fmaf(-xo.x, yo.x, sxy.x));
            sxy.y = fmaf(xn.y, yn.y, fmaf(-xo.y, yo.y, sxy.y));
            sxy.z = fmaf(xn.z, yn.z, fmaf(-xo.z, yo.z, sxy.z));
            sxy.w = fmaf(xn.w, yn.w, fmaf(-xo.w, yo.w, sxy.w));
            spp.x = fmaf(xn.x, xn.x, fmaf(yn.x, yn.x, fmaf(-xo.x, xo.x, fmaf(-yo.x, yo.x, spp.x))));
            spp.y = fmaf(xn.y, xn.y, fmaf(yn.y, yn.y, fmaf(-xo.y, xo.y, fmaf(-yo.y, yo.y, spp.y))));
            spp.z = fmaf(xn.z, xn.z, fmaf(yn.z, yn.z, fmaf(-xo.z, xo.z, fmaf(-yo.z, yo.z, spp.z))));
            spp.w = fmaf(xn.w, xn.w, fmaf(yn.w, yn.w, fmaf(-xo.w, xo.w, fmaf(-yo.w, yo.w, spp.w))));
            xh[slot] = xn; yh[slot] = yn;

            // Horizontal 7-tap sliding window via cross-lane shuffles.
            float wx[4], wy[4], wpp[4], wxy[4];
            #define HWIN(S, WA)                                            \
            {                                                              \
                const float bx = __shfl_down(S.x, 1);                      \
                const float by = __shfl_down(S.y, 1);                      \
                const float bz = __shfl_down(S.z, 1);                      \
                const float bw = __shfl_down(S.w, 1);                      \
                const float cx = __shfl_down(S.x, 2);                      \
                const float cy = __shfl_down(S.y, 2);                      \
                WA[0] = S.x + S.y + S.z + S.w + bx + by + bz;              \
                WA[1] = WA[0] - S.x + bw;                                  \
                WA[2] = WA[1] - S.y + cx;                                  \
                WA[3] = WA[2] - S.z + cy;                                  \
            }
            HWIN(sx,  wx)
            HWIN(sy,  wy)
            HWIN(spp, wpp)
            HWIN(sxy, wxy)
            #undef HWIN

            // SSIM for this lane's 4 output columns (constants folded).
            #pragma unroll
            for (int s = 0; s < 4; ++s) {
                const float P  = wx[s] * wy[s];
                const float Qs = fmaf(wy[s], wy[s], wx[s] * wx[s]);
                const float A1 = fmaf(C2A, P, C1);
                const float B1 = fmaf(AA, Qs, C1);
                const float A2 = fmaf(T1, wxy[s], fmaf(T2, P, C2));
                const float B2 = fmaf(T3, wpp[s], fmaf(T4, Qs, C2));
                const float S  = (A1 * A2) * __builtin_amdgcn_rcpf(B1 * B2);
                if (4 * lane + s < OWID) lsum += S;   // mask cols >= 250
            }
        }
    }

    // Wave reduction -> one partial per wave.
    #pragma unroll
    for (int off = 32; off > 0; off >>= 1)
        lsum += __shfl_down(lsum, off, 64);
    if (lane == 0) partial[wid] = lsum;   // wid == img*NBANDS + band
}

__global__ __launch_bounds__(256) void ssim_reduce_kernel(
    const float* __restrict__ partial, float* __restrict__ out)
{
    const int tid = threadIdx.x;
    double acc = 0.0;
    for (int i = tid; i < NBLK; i += 256)
        acc += (double)partial[i];
    #pragma unroll
    for (int off = 32; off > 0; off >>= 1)
        acc += __shfl_down(acc, off, 64);
    __shared__ double wsumd[4];
    if ((tid & 63) == 0) wsumd[tid >> 6] = acc;
    __syncthreads();
    if (tid == 0) {
        double total = wsumd[0] + wsumd[1] + wsumd[2] + wsumd[3];
        float loss = (float)(1.0 - total / 16000000.0);
        out[0] = loss; out[1] = loss; out[2] = loss; out[3] = loss;
    }
}

extern "C" void kernel_launch(void* const* d_in, const int* in_sizes, int n_in,
                              void* d_out, int out_size, void* d_ws, size_t ws_size,
                              hipStream_t stream) {
    const float* X = (const float*)d_in[0];
    const float* Y = (const float*)d_in[1];
    // d_in[2] is the uniform 7x7 filter (1/49 everywhere) — constant-folded.
    float* out = (float*)d_out;
    float* partial = (float*)d_ws;   // 6400 floats = 25.6 KB

    hipLaunchKernelGGL(ssim_band_kernel, dim3(NBLOCKS), dim3(256), 0, stream,
                       X, Y, partial);
    hipLaunchKernelGGL(ssim_reduce_kernel, dim3(1), dim3(256), 0, stream,
                       partial, out);
}

// Round 4
// 189.019 us; speedup vs baseline: 1.0764x; 1.0764x over previous
//
#include <hip/hip_runtime.h>

#define H 256
#define W 256
#define W4 (W / 4)            // 64 float4 per image row
#define OWID 250
#define NIMG 256              // B*D
#define BAND 10               // output rows per wave; 25*10 = 250 exactly
#define NBANDS 25
#define NBLK (NBANDS * NIMG)  // 6400 partials
#define RIN 16                // input rows per band: BAND + 6, uniform for ALL bands
#define WPB 4                 // waves per block
#define NBLOCKS (NBLK / WPB)  // 1600 blocks of 256 threads

__device__ __forceinline__ float4 f4zero() { return make_float4(0.f, 0.f, 0.f, 0.f); }

// __launch_bounds__(256, 6): VGPR cap = 512/6 ~= 85. This body compiles to
// ~60 VGPR unconstrained (round 2), so no spills; 6 blocks/CU x 4 waves =
// 24 waves/CU (75% occupancy ceiling). Round 3's (256, 8) forced a 64-VGPR
// tier -> allocator spilled history to scratch (WRITE_SIZE 200KB -> 113MB,
// kernel 68 -> 99 us). Do NOT raise the second arg above 6.
__global__ __launch_bounds__(256, 6) void ssim_band_kernel(
    const float* __restrict__ X, const float* __restrict__ Y,
    float* __restrict__ partial)
{
    // 4 independent waves per block (no barriers, no LDS).
    const int lane = threadIdx.x & 63;          // 0..63, owns cols 4*lane..+3
    const int wid  = blockIdx.x * WPB + (threadIdx.x >> 6);  // 0..6399
    const int img  = wid / NBANDS;              // 0..255
    const int band = wid % NBANDS;              // 0..24 (adjacent bands share
                                                //        halo rows -> L1/L2)
    const int r0 = band * BAND;

    const float4* Xp = (const float4*)X + ((size_t)img * H + r0) * W4 + lane;
    const float4* Yp = (const float4*)Y + ((size_t)img * H + r0) * W4 + lane;

    // 7-deep circular history of raw x,y (registers; all indices static).
    float4 xh[7], yh[7];
    // 4 vertical moments: sx, sy, sxy, and spp = Σ(x²+y²).
    float4 sx = f4zero(), sy = f4zero(), sxy = f4zero(), spp = f4zero();

    // Depth-2 prefetch pipeline.
    float4 px[2], py[2];
    px[0] = Xp[0];      py[0] = Yp[0];
    px[1] = Xp[W4];     py[1] = Yp[W4];
    xh[6] = f4zero();   yh[6] = f4zero();   // row-6 subtracts nothing

    // SSIM constants with 1/49 (=a) and 49/48 (=covn) folded in.
    const float C1  = 1e-4f;            // (0.01)^2
    const float C2  = 9e-4f;            // (0.03)^2
    const float AA  = 1.f / 2401.f;     // a^2
    const float C2A = 2.f / 2401.f;     // 2 a^2
    const float T1  = 1.f / 24.f;       // 2 covn a
    const float T2  = -1.f / 1176.f;    // -2 covn a^2
    const float T3  = 1.f / 48.f;       // covn a
    const float T4  = -1.f / 2352.f;    // -covn a^2
    float lsum = 0.0f;

    #pragma unroll
    for (int r = 0; r < RIN; ++r) {
        // Consume row r (loaded 2 iterations ago), then refill the slot with
        // row r+2 so 2 row-pairs stay in flight.
        const float4 xn = px[r & 1], yn = py[r & 1];
        if (r + 2 < RIN) {
            px[r & 1] = Xp[(r + 2) * W4];
            py[r & 1] = Yp[(r + 2) * W4];
        }

        if (r < 6) {
            // Prologue rows: accumulate only.
            xh[r] = xn; yh[r] = yn;
            sx.x += xn.x; sx.y += xn.y; sx.z += xn.z; sx.w += xn.w;
            sy.x += yn.x; sy.y += yn.y; sy.z += yn.z; sy.w += yn.w;
            sxy.x = fmaf(xn.x, yn.x, sxy.x);
            sxy.y = fmaf(xn.y, yn.y, sxy.y);
            sxy.z = fmaf(xn.z, yn.z, sxy.z);
            sxy.w = fmaf(xn.w, yn.w, sxy.w);
            spp.x = fmaf(xn.x, xn.x, fmaf(yn.x, yn.x, spp.x));
            spp.y = fmaf(xn.y, xn.y, fmaf(yn.y, yn.y, spp.y));
            spp.z = fmaf(xn.z, xn.z, fmaf(yn.z, yn.z, spp.z));
            spp.w = fmaf(xn.w, xn.w, fmaf(yn.w, yn.w, spp.w));
        } else {
            const int slot = r % 7;            // static under full unroll
            const float4 xo = xh[slot], yo = yh[slot];

            // Vertical slide: + entering row r, - leaving row r-7.
            sx.x += xn.x - xo.x; sx.y += xn.y - xo.y;
            sx.z += xn.z - xo.z; sx.w += xn.w - xo.w;
            sy.x += yn.x - yo.x; sy.y += yn.y - yo.y;
            sy.z += yn.z - yo.z; sy.w += yn.w - yo.w;
            sxy.x = fmaf(xn.x, yn.x, fmaf(-xo.x, yo.x, sxy.x));
            sxy.y = fmaf(xn.y, yn.y, fmaf(-xo.y, yo.y, sxy.y));
            sxy.z = fmaf(xn.z, yn.z, fmaf(-xo.z, yo.z, sxy.z));
            sxy.w = fmaf(xn.w, yn.w, fmaf(-xo.w, yo.w, sxy.w));
            spp.x = fmaf(xn.x, xn.x, fmaf(yn.x, yn.x, fmaf(-xo.x, xo.x, fmaf(-yo.x, yo.x, spp.x))));
            spp.y = fmaf(xn.y, xn.y, fmaf(yn.y, yn.y, fmaf(-xo.y, xo.y, fmaf(-yo.y, yo.y, spp.y))));
            spp.z = fmaf(xn.z, xn.z, fmaf(yn.z, yn.z, fmaf(-xo.z, xo.z, fmaf(-yo.z, yo.z, spp.z))));
            spp.w = fmaf(xn.w, xn.w, fmaf(yn.w, yn.w, fmaf(-xo.w, xo.w, fmaf(-yo.w, yo.w, spp.w))));
            xh[slot] = xn; yh[slot] = yn;

            // Horizontal 7-tap sliding window via cross-lane shuffles.
            float wx[4], wy[4], wpp[4], wxy[4];
            #define HWIN(S, WA)                                            \
            {                                                              \
                const float bx = __shfl_down(S.x, 1);                      \
                const float by = __shfl_down(S.y, 1);                      \
                const float bz = __shfl_down(S.z, 1);                      \
                const float bw = __shfl_down(S.w, 1);                      \
                const float cx = __shfl_down(S.x, 2);                      \
                const float cy = __shfl_down(S.y, 2);                      \
                WA[0] = S.x + S.y + S.z + S.w + bx + by + bz;              \
                WA[1] = WA[0] - S.x + bw;                                  \
                WA[2] = WA[1] - S.y + cx;                                  \
                WA[3] = WA[2] - S.z + cy;                                  \
            }
            HWIN(sx,  wx)
            HWIN(sy,  wy)
            HWIN(spp, wpp)
            HWIN(sxy, wxy)
            #undef HWIN

            // SSIM for this lane's 4 output columns (constants folded).
            #pragma unroll
            for (int s = 0; s < 4; ++s) {
                const float P  = wx[s] * wy[s];
                const float Qs = fmaf(wy[s], wy[s], wx[s] * wx[s]);
                const float A1 = fmaf(C2A, P, C1);
                const float B1 = fmaf(AA, Qs, C1);
                const float A2 = fmaf(T1, wxy[s], fmaf(T2, P, C2));
                const float B2 = fmaf(T3, wpp[s], fmaf(T4, Qs, C2));
                const float S  = (A1 * A2) * __builtin_amdgcn_rcpf(B1 * B2);
                if (4 * lane + s < OWID) lsum += S;   // mask cols >= 250
            }
        }
    }

    // Wave reduction -> one partial per wave.
    #pragma unroll
    for (int off = 32; off > 0; off >>= 1)
        lsum += __shfl_down(lsum, off, 64);
    if (lane == 0) partial[wid] = lsum;   // wid == img*NBANDS + band
}

__global__ __launch_bounds__(256) void ssim_reduce_kernel(
    const float* __restrict__ partial, float* __restrict__ out)
{
    const int tid = threadIdx.x;
    double acc = 0.0;
    for (int i = tid; i < NBLK; i += 256)
        acc += (double)partial[i];
    #pragma unroll
    for (int off = 32; off > 0; off >>= 1)
        acc += __shfl_down(acc, off, 64);
    __shared__ double wsumd[4];
    if ((tid & 63) == 0) wsumd[tid >> 6] = acc;
    __syncthreads();
    if (tid == 0) {
        double total = wsumd[0] + wsumd[1] + wsumd[2] + wsumd[3];
        float loss = (float)(1.0 - total / 16000000.0);
        out[0] = loss; out[1] = loss; out[2] = loss; out[3] = loss;
    }
}

extern "C" void kernel_launch(void* const* d_in, const int* in_sizes, int n_in,
                              void* d_out, int out_size, void* d_ws, size_t ws_size,
                              hipStream_t stream) {
    const float* X = (const float*)d_in[0];
    const float* Y = (const float*)d_in[1];
    // d_in[2] is the uniform 7x7 filter (1/49 everywhere) — constant-folded.
    float* out = (float*)d_out;
    float* partial = (float*)d_ws;   // 6400 floats = 25.6 KB

    hipLaunchKernelGGL(ssim_band_kernel, dim3(NBLOCKS), dim3(256), 0, stream,
                       X, Y, partial);
    hipLaunchKernelGGL(ssim_reduce_kernel, dim3(1), dim3(256), 0, stream,
                       partial, out);
}

// Round 5
// 159.357 us; speedup vs baseline: 1.2767x; 1.1861x over previous
//
#include <hip/hip_runtime.h>

#define H 256
#define W 256
#define W4 (W / 4)            // 64 float4 per image row
#define OWID 250
#define NIMG 256              // B*D
#define BAND 10               // output rows per wave; 25*10 = 250 exactly
#define NBANDS 25
#define NBLK (NBANDS * NIMG)  // 6400 partials
#define RIN 16                // input rows per band: BAND + 6, uniform for ALL bands
#define WPB 4                 // waves per block
#define NBLOCKS (NBLK / WPB)  // 1600 blocks of 256 threads

__device__ __forceinline__ float4 f4zero() { return make_float4(0.f, 0.f, 0.f, 0.f); }

// NOTE (measured, rounds 3+4): adding a min-waves/EU arg to __launch_bounds__
// on this body makes the allocator pick a tiny VGPR budget (32/40) and spill
// the float4 pipeline arrays to scratch: WRITE_SIZE 0.2 MB -> 85-114 MB,
// kernel 68 -> 87-99 us. Leave it as plain __launch_bounds__(256).
__global__ __launch_bounds__(256) void ssim_band_kernel(
    const float* __restrict__ X, const float* __restrict__ Y,
    float* __restrict__ partial)
{
    // 4 independent waves per block (no barriers, no LDS).
    // Register-pressure design: NO in-register row history. The row leaving
    // the 7-row vertical window (row r-7) was fetched 7 iterations ago and is
    // L1/L2-resident; re-load it through its own depth-2 prefetch pipeline
    // (ox/oy) instead of holding a 7-deep float4 history (56 VGPRs) alive.
    const int lane = threadIdx.x & 63;          // 0..63, owns cols 4*lane..+3
    const int wid  = blockIdx.x * WPB + (threadIdx.x >> 6);  // 0..6399
    const int img  = wid / NBANDS;              // 0..255
    const int band = wid % NBANDS;              // 0..24 (adjacent bands share
                                                //        halo rows -> L1/L2)
    const int r0 = band * BAND;

    const float4* Xp = (const float4*)X + ((size_t)img * H + r0) * W4 + lane;
    const float4* Yp = (const float4*)Y + ((size_t)img * H + r0) * W4 + lane;

    // 4 vertical moments: sx, sy, sxy, and spp = Σ(x²+y²).
    float4 sx = f4zero(), sy = f4zero(), sxy = f4zero(), spp = f4zero();

    // Depth-2 prefetch pipelines: new rows (px/py) and leaving rows (ox/oy).
    // All indices are static under the full unroll ((r+2)&1 == r&1, so each
    // slot is read-then-refilled in the same iteration).
    float4 px[2], py[2], ox[2], oy[2];
    px[0] = Xp[0];      py[0] = Yp[0];
    px[1] = Xp[W4];     py[1] = Yp[W4];

    // SSIM constants with 1/49 (=a) and 49/48 (=covn) folded in.
    const float C1  = 1e-4f;            // (0.01)^2
    const float C2  = 9e-4f;            // (0.03)^2
    const float AA  = 1.f / 2401.f;     // a^2
    const float C2A = 2.f / 2401.f;     // 2 a^2
    const float T1  = 1.f / 24.f;       // 2 covn a
    const float T2  = -1.f / 1176.f;    // -2 covn a^2
    const float T3  = 1.f / 48.f;       // covn a
    const float T4  = -1.f / 2352.f;    // -covn a^2
    float lsum = 0.0f;

    #pragma unroll
    for (int r = 0; r < RIN; ++r) {
        // Consume new row r (issued 2 iterations ago), refill slot with r+2.
        const float4 xn = px[r & 1], yn = py[r & 1];
        if (r + 2 < RIN) {
            px[r & 1] = Xp[(r + 2) * W4];
            py[r & 1] = Yp[(r + 2) * W4];
        }
        // Leaving row for iteration r is row r-7 (first needed at r=7).
        float4 xo = f4zero(), yo = f4zero();
        if (r >= 7) { xo = ox[r & 1]; yo = oy[r & 1]; }
        // Issue the leaving-row load for iteration r+2 (row r-5). These hit
        // L1/L2 (fetched from HBM 7 rows earlier).
        if (r >= 5 && r <= RIN - 3) {
            ox[r & 1] = Xp[(r - 5) * W4];
            oy[r & 1] = Yp[(r - 5) * W4];
        }

        if (r < 6) {
            // Prologue rows: accumulate only.
            sx.x += xn.x; sx.y += xn.y; sx.z += xn.z; sx.w += xn.w;
            sy.x += yn.x; sy.y += yn.y; sy.z += yn.z; sy.w += yn.w;
            sxy.x = fmaf(xn.x, yn.x, sxy.x);
            sxy.y = fmaf(xn.y, yn.y, sxy.y);
            sxy.z = fmaf(xn.z, yn.z, sxy.z);
            sxy.w = fmaf(xn.w, yn.w, sxy.w);
            spp.x = fmaf(xn.x, xn.x, fmaf(yn.x, yn.x, spp.x));
            spp.y = fmaf(xn.y, xn.y, fmaf(yn.y, yn.y, spp.y));
            spp.z = fmaf(xn.z, xn.z, fmaf(yn.z, yn.z, spp.z));
            spp.w = fmaf(xn.w, xn.w, fmaf(yn.w, yn.w, spp.w));
        } else {
            // Vertical slide: + entering row r, - leaving row r-7 (zero at r=6).
            sx.x += xn.x - xo.x; sx.y += xn.y - xo.y;
            sx.z += xn.z - xo.z; sx.w += xn.w - xo.w;
            sy.x += yn.x - yo.x; sy.y += yn.y - yo.y;
            sy.z += yn.z - yo.z; sy.w += yn.w - yo.w;
            sxy.x = fmaf(xn.x, yn.x, fmaf(-xo.x, yo.x, sxy.x));
            sxy.y = fmaf(xn.y, yn.y, fmaf(-xo.y, yo.y, sxy.y));
            sxy.z = fmaf(xn.z, yn.z, fmaf(-xo.z, yo.z, sxy.z));
            sxy.w = fmaf(xn.w, yn.w, fmaf(-xo.w, yo.w, sxy.w));
            spp.x = fmaf(xn.x, xn.x, fmaf(yn.x, yn.x, fmaf(-xo.x, xo.x, fmaf(-yo.x, yo.x, spp.x))));
            spp.y = fmaf(xn.y, xn.y, fmaf(yn.y, yn.y, fmaf(-xo.y, xo.y, fmaf(-yo.y, yo.y, spp.y))));
            spp.z = fmaf(xn.z, xn.z, fmaf(yn.z, yn.z, fmaf(-xo.z, xo.z, fmaf(-yo.z, yo.z, spp.z))));
            spp.w = fmaf(xn.w, xn.w, fmaf(yn.w, yn.w, fmaf(-xo.w, xo.w, fmaf(-yo.w, yo.w, spp.w))));

            // Horizontal 7-tap sliding window via cross-lane shuffles.
            // Lane L col s window = cols 4L+s .. 4L+s+6: needs lane L+1's 4
            // sums and lane L+2's first 2. Out-of-range shuffles (lanes 62/63)
            // return own values and only feed columns masked below.
            float wx[4], wy[4], wpp[4], wxy[4];
            #define HWIN(S, WA)                                            \
            {                                                              \
                const float bx = __shfl_down(S.x, 1);                      \
                const float by = __shfl_down(S.y, 1);                      \
                const float bz = __shfl_down(S.z, 1);                      \
                const float bw = __shfl_down(S.w, 1);                      \
                const float cx = __shfl_down(S.x, 2);                      \
                const float cy = __shfl_down(S.y, 2);                      \
                WA[0] = S.x + S.y + S.z + S.w + bx + by + bz;              \
                WA[1] = WA[0] - S.x + bw;                                  \
                WA[2] = WA[1] - S.y + cx;                                  \
                WA[3] = WA[2] - S.z + cy;                                  \
            }
            HWIN(sx,  wx)
            HWIN(sy,  wy)
            HWIN(spp, wpp)
            HWIN(sxy, wxy)
            #undef HWIN

            // SSIM for this lane's 4 output columns (constants folded):
            //   A1 = 2a²·wx·wy + C1
            //   B1 = a²·(wx²+wy²) + C1
            //   A2 = 2covn·a·wxy − 2covn·a²·wx·wy + C2
            //   B2 = covn·a·wpp − covn·a²·(wx²+wy²) + C2
            #pragma unroll
            for (int s = 0; s < 4; ++s) {
                const float P  = wx[s] * wy[s];
                const float Qs = fmaf(wy[s], wy[s], wx[s] * wx[s]);
                const float A1 = fmaf(C2A, P, C1);
                const float B1 = fmaf(AA, Qs, C1);
                const float A2 = fmaf(T1, wxy[s], fmaf(T2, P, C2));
                const float B2 = fmaf(T3, wpp[s], fmaf(T4, Qs, C2));
                const float S  = (A1 * A2) * __builtin_amdgcn_rcpf(B1 * B2);
                if (4 * lane + s < OWID) lsum += S;   // mask cols >= 250
            }
        }
    }

    // Wave reduction -> one partial per wave.
    #pragma unroll
    for (int off = 32; off > 0; off >>= 1)
        lsum += __shfl_down(lsum, off, 64);
    if (lane == 0) partial[wid] = lsum;   // wid == img*NBANDS + band
}

__global__ __launch_bounds__(256) void ssim_reduce_kernel(
    const float* __restrict__ partial, float* __restrict__ out)
{
    const int tid = threadIdx.x;
    double acc = 0.0;
    for (int i = tid; i < NBLK; i += 256)
        acc += (double)partial[i];
    #pragma unroll
    for (int off = 32; off > 0; off >>= 1)
        acc += __shfl_down(acc, off, 64);
    __shared__ double wsumd[4];
    if ((tid & 63) == 0) wsumd[tid >> 6] = acc;
    __syncthreads();
    if (tid == 0) {
        double total = wsumd[0] + wsumd[1] + wsumd[2] + wsumd[3];
        float loss = (float)(1.0 - total / 16000000.0);
        out[0] = loss; out[1] = loss; out[2] = loss; out[3] = loss;
    }
}

extern "C" void kernel_launch(void* const* d_in, const int* in_sizes, int n_in,
                              void* d_out, int out_size, void* d_ws, size_t ws_size,
                              hipStream_t stream) {
    const float* X = (const float*)d_in[0];
    const float* Y = (const float*)d_in[1];
    // d_in[2] is the uniform 7x7 filter (1/49 everywhere) — constant-folded.
    float* out = (float*)d_out;
    float* partial = (float*)d_ws;   // 6400 floats = 25.6 KB

    hipLaunchKernelGGL(ssim_band_kernel, dim3(NBLOCKS), dim3(256), 0, stream,
                       X, Y, partial);
    hipLaunchKernelGGL(ssim_reduce_kernel, dim3(1), dim3(256), 0, stream,
                       partial, out);
}